// Round 4
// baseline (110.466 us; speedup 1.0000x reference)
//
#include <hip/hip_runtime.h>

#define K_RBF   32
#define LUT_N   1024
#define LUT_LO  (-8.0f)
#define LUT_HI  (8.0f)
// h = 16/1024 = 0.015625, inv_h = 64
#define LUT_INVH 64.0f

// Reference constants at float32 precision, exactly as jnp.float32(...)
#define DT_F      0.005f
#define M_INV_F   ((float)(1.0 / 95.452))
#define OFFST_F   (-3.2902f)
#define F_V_F     214.9261f
#define F_C_F     19.3607f

// ---------------------------------------------------------------------------
// Prep: tabulate f(x) = b + sum_k w_k exp(-(s_k (x - c_k))^2) on a uniform
// grid. Entry i stores {f(x_i), f(x_{i+1})} so the main kernel's lerp is a
// single aligned 8B LDS read.
// ---------------------------------------------------------------------------
__global__ void build_lut(const float* __restrict__ centers,
                          const float* __restrict__ log_sigmas,
                          const float* __restrict__ w,
                          const float* __restrict__ bptr,
                          float2* __restrict__ lut) {
    int i = blockIdx.x * blockDim.x + threadIdx.x;
    if (i >= LUT_N) return;
    const float H = (LUT_HI - LUT_LO) / (float)LUT_N;
    float x0 = LUT_LO + (float)i * H;
    float x1 = x0 + H;
    float f0 = bptr[0], f1 = f0;
#pragma unroll 8
    for (int k = 0; k < K_RBF; ++k) {
        float s = __expf(log_sigmas[k]);
        float c = centers[k];
        float wk = w[k];
        float d0 = s * (x0 - c);
        float d1 = s * (x1 - c);
        f0 = fmaf(wk, __expf(-d0 * d0), f0);
        f1 = fmaf(wk, __expf(-d1 * d1), f1);
    }
    lut[i] = make_float2(f0, f1);
}

// ---------------------------------------------------------------------------
// Main: grid-stride, 4 elements per thread-iteration. f,f' from the LDS LUT
// (lerp value + slope). RK4 tail collapsed algebraically:
//   k2 = k1*(1 - M_INV*h *(FVC+f')),  k4 = k1*(1 - M_INV*DT*(FVC+f'))
//   st1 = C6*k1*(6 - M_INV*(4h+DT)*(FVC+f'))
//   st0 = C6*(6x + (4h+DT)*k1) = DT*x + C6*0.015*k1
// (identical math to the explicit Taylor form; y0 is dead; yd==k1, k3==k2.)
// ---------------------------------------------------------------------------
__launch_bounds__(256)
__global__ void rk4_rbf_kernel(const float4* __restrict__ u4,
                               const float4* __restrict__ states4,
                               const float2* __restrict__ lut_g,
                               float4* __restrict__ out4,
                               int n_quads) {
    __shared__ float2 LUT[LUT_N];   // 8 KB
    {
        const float4* src = (const float4*)lut_g;
        float4* dst = (float4*)LUT;
#pragma unroll
        for (int j = 0; j < LUT_N / 2 / 256; ++j)
            dst[threadIdx.x + 256 * j] = src[threadIdx.x + 256 * j];
    }
    __syncthreads();

    const float FVC = F_V_F + F_C_F;
    const float C6  = DT_F / 6.0f;
    const float C1  = 0.015f * M_INV_F;   // M_INV*(4h+DT)
    const float C2  = C6 * 0.015f;        // C6*(4h+DT)

    int stride = gridDim.x * blockDim.x;
    for (int i = blockIdx.x * blockDim.x + threadIdx.x; i < n_quads; i += stride) {
        float4 sA = states4[2 * i];
        float4 sB = states4[2 * i + 1];
        float4 uu = u4[i];

        float x[4]  = { sA.y, sA.w, sB.y, sB.w };   // y1 (y0 is dead)
        float uv[4] = { uu.x, uu.y, uu.z, uu.w };

        float o[8];
#pragma unroll
        for (int e = 0; e < 4; ++e) {
            float xc  = fminf(fmaxf(x[e], LUT_LO + 1e-3f), LUT_HI - 1e-3f);
            float t   = (xc - LUT_LO) * LUT_INVH;
            int   idx = (int)t;
            float fr  = t - (float)idx;
            float2 L  = LUT[idx];
            float df  = L.y - L.x;
            float f   = fmaf(fr, df, L.x);          // f(x) incl. b
            float fp  = df * LUT_INVH;              // f'(x)

            float k1 = (uv[e] - FVC * x[e] - (OFFST_F + f)) * M_INV_F;
            float g  = 6.0f - C1 * (FVC + fp);
            o[2 * e]     = fmaf(C2, k1, DT_F * x[e]);   // st0
            o[2 * e + 1] = C6 * k1 * g;                 // st1
        }

        out4[2 * i]     = make_float4(o[0], o[1], o[2], o[3]);
        out4[2 * i + 1] = make_float4(o[4], o[5], o[6], o[7]);
    }
}

extern "C" void kernel_launch(void* const* d_in, const int* in_sizes, int n_in,
                              void* d_out, int out_size, void* d_ws, size_t ws_size,
                              hipStream_t stream) {
    const float* u        = (const float*)d_in[0];   // (B,)
    const float* states   = (const float*)d_in[1];   // (B,2)
    const float* centers  = (const float*)d_in[2];   // (32,)
    const float* logsig   = (const float*)d_in[3];   // (32,)
    const float* w        = (const float*)d_in[4];   // (32,)
    const float* b        = (const float*)d_in[5];   // (1,)

    float2* lut = (float2*)d_ws;                     // 1024 * 8B = 8 KB scratch

    build_lut<<<LUT_N / 256, 256, 0, stream>>>(centers, logsig, w, b, lut);

    int B = in_sizes[0];
    int n_quads = B / 4;                             // B = 4194304
    int block = 256;
    int grid  = 1024;                                // grid-stride: 4 quads/thread
    rk4_rbf_kernel<<<grid, block, 0, stream>>>(
        (const float4*)u, (const float4*)states, lut, (float4*)d_out, n_quads);
}

// Round 6
// 109.854 us; speedup vs baseline: 1.0056x; 1.0056x over previous
//
#include <hip/hip_runtime.h>

#define K_RBF   32
#define LUT_N   1024
#define LUT_LO  (-8.0f)
#define LUT_HI  (8.0f)
// h = 16/1024 = 0.015625, inv_h = 64
#define LUT_INVH 64.0f

// Reference constants at float32 precision, exactly as jnp.float32(...)
#define DT_F      0.005f
#define M_INV_F   ((float)(1.0 / 95.452))
#define OFFST_F   (-3.2902f)
#define F_V_F     214.9261f
#define F_C_F     19.3607f

// Native clang vectors — accepted by __builtin_nontemporal_{load,store}
// (HIP_vector_type float4/float2 are structs and are rejected).
typedef float vfloat4 __attribute__((ext_vector_type(4)));
typedef float vfloat2 __attribute__((ext_vector_type(2)));

// ---------------------------------------------------------------------------
// Prep: tabulate f(x) = b + sum_k w_k exp(-(s_k (x - c_k))^2) on a uniform
// grid. Entry i stores {f(x_i), f(x_{i+1})} so the main kernel's lerp is a
// single aligned 8B LDS read.
// ---------------------------------------------------------------------------
__global__ void build_lut(const float* __restrict__ centers,
                          const float* __restrict__ log_sigmas,
                          const float* __restrict__ w,
                          const float* __restrict__ bptr,
                          float2* __restrict__ lut) {
    int i = blockIdx.x * blockDim.x + threadIdx.x;
    if (i >= LUT_N) return;
    const float H = (LUT_HI - LUT_LO) / (float)LUT_N;
    float x0 = LUT_LO + (float)i * H;
    float x1 = x0 + H;
    float f0 = bptr[0], f1 = f0;
#pragma unroll 8
    for (int k = 0; k < K_RBF; ++k) {
        float s = __expf(log_sigmas[k]);
        float c = centers[k];
        float wk = w[k];
        float d0 = s * (x0 - c);
        float d1 = s * (x1 - c);
        f0 = fmaf(wk, __expf(-d0 * d0), f0);
        f1 = fmaf(wk, __expf(-d1 * d1), f1);
    }
    lut[i] = make_float2(f0, f1);
}

// ---------------------------------------------------------------------------
// Main: grid-stride, 2 elements per thread-iteration so that EVERY global
// stream is unit-stride across lanes (16B/lane states, 8B/lane u, 16B/lane
// out — no 32B-stride pairs). f,f' from LDS-LUT lerp; RK4 tail collapsed:
//   st1 = C6*k1*(6 - M_INV*(4h+DT)*(FVC+f'))
//   st0 = DT*x + C6*(4h+DT)*k1
// (identical math to explicit Taylor-RK4; y0 dead; yd==k1, k3==k2.)
// All big streams nontemporal (no reuse).
// ---------------------------------------------------------------------------
__launch_bounds__(256)
__global__ void rk4_rbf_kernel(const vfloat2* __restrict__ u2,
                               const vfloat4* __restrict__ states4,
                               const float2* __restrict__ lut_g,
                               vfloat4* __restrict__ out4,
                               int n_pairs) {
    __shared__ float2 LUT[LUT_N];   // 8 KB
    {
        const float4* src = (const float4*)lut_g;
        float4* dst = (float4*)LUT;
#pragma unroll
        for (int j = 0; j < LUT_N / 2 / 256; ++j)
            dst[threadIdx.x + 256 * j] = src[threadIdx.x + 256 * j];
    }
    __syncthreads();

    const float FVC = F_V_F + F_C_F;
    const float C6  = DT_F / 6.0f;
    const float C1  = 0.015f * M_INV_F;   // M_INV*(4h+DT)
    const float C2  = C6 * 0.015f;        // C6*(4h+DT)

    int stride = gridDim.x * blockDim.x;
    for (int i = blockIdx.x * blockDim.x + threadIdx.x; i < n_pairs; i += stride) {
        vfloat4 s  = __builtin_nontemporal_load(&states4[i]);  // y0a,y1a,y0b,y1b
        vfloat2 uu = __builtin_nontemporal_load(&u2[i]);

        float x[2]  = { s.y, s.w };     // y1 (y0 is dead)
        float uv[2] = { uu.x, uu.y };
        float o[4];
#pragma unroll
        for (int e = 0; e < 2; ++e) {
            float xc  = fminf(fmaxf(x[e], LUT_LO + 1e-3f), LUT_HI - 1e-3f);
            float t   = (xc - LUT_LO) * LUT_INVH;
            int   idx = (int)t;
            float fr  = t - (float)idx;
            float2 L  = LUT[idx];
            float df  = L.y - L.x;
            float f   = fmaf(fr, df, L.x);          // f(x) incl. b
            float fp  = df * LUT_INVH;              // f'(x)

            float k1 = (uv[e] - FVC * x[e] - (OFFST_F + f)) * M_INV_F;
            float g  = 6.0f - C1 * (FVC + fp);
            o[2 * e]     = fmaf(C2, k1, DT_F * x[e]);   // st0
            o[2 * e + 1] = C6 * k1 * g;                 // st1
        }

        vfloat4 ov = { o[0], o[1], o[2], o[3] };
        __builtin_nontemporal_store(ov, &out4[i]);
    }
}

extern "C" void kernel_launch(void* const* d_in, const int* in_sizes, int n_in,
                              void* d_out, int out_size, void* d_ws, size_t ws_size,
                              hipStream_t stream) {
    const float* u        = (const float*)d_in[0];   // (B,)
    const float* states   = (const float*)d_in[1];   // (B,2)
    const float* centers  = (const float*)d_in[2];   // (32,)
    const float* logsig   = (const float*)d_in[3];   // (32,)
    const float* w        = (const float*)d_in[4];   // (32,)
    const float* b        = (const float*)d_in[5];   // (1,)

    float2* lut = (float2*)d_ws;                     // 1024 * 8B = 8 KB scratch

    build_lut<<<LUT_N / 256, 256, 0, stream>>>(centers, logsig, w, b, lut);

    int B = in_sizes[0];
    int n_pairs = B / 2;                             // 2,097,152
    int block = 256;
    int grid  = 2048;                                // grid-stride: 4 pairs/thread
    rk4_rbf_kernel<<<grid, block, 0, stream>>>(
        (const vfloat2*)u, (const vfloat4*)states, lut, (vfloat4*)d_out, n_pairs);
}

// Round 7
// 105.651 us; speedup vs baseline: 1.0456x; 1.0398x over previous
//
#include <hip/hip_runtime.h>

#define K_RBF   32
#define LUT_N   256           // points over [LUT_LO, LUT_HI]; intervals 0..254
#define LUT_LO  (-8.0f)
#define LUT_HI  (8.0f)
// h = 16/256 = 0.0625, inv_h = 16
#define LUT_INVH 16.0f

// Reference constants at float32 precision, exactly as jnp.float32(...)
#define DT_F      0.005f
#define M_INV_F   ((float)(1.0 / 95.452))
#define OFFST_F   (-3.2902f)
#define F_V_F     214.9261f
#define F_C_F     19.3607f

#if __has_builtin(__builtin_amdgcn_exp2f)
#define EXP2(x) __builtin_amdgcn_exp2f(x)
#else
#define EXP2(x) exp2f(x)
#endif

// Native clang vectors — accepted by __builtin_nontemporal_{load,store}.
typedef float vfloat4 __attribute__((ext_vector_type(4)));
typedef float vfloat2 __attribute__((ext_vector_type(2)));

// ---------------------------------------------------------------------------
// Single fused kernel.
// Phase 1 (per block, ~0.15 us, hidden under streaming): build a 256-point
//   table of f(x) = b + sum_k w_k exp(-(s_k(x-c_k))^2) in LDS.
//   phi_k = exp2(q_k), q_k = A x^2 + B x + E with log2e folded in; 32 threads
//   first stage {A,B,E,w}, then each thread tabulates one grid point.
// Phase 2: grid-stride streaming, 2 elements/thread-iter, all streams
//   unit-stride (16B states, 8B u, 16B out per lane), nontemporal.
//   f,f' from LUT lerp (idx clamped to [0,254]); RK4 tail collapsed:
//     st1 = C6*k1*(6 - M_INV*(4h+DT)*(FVC+f'))
//     st0 = DT*x + C6*(4h+DT)*k1
//   (identical math to explicit Taylor-RK4; y0 dead; yd==k1, k3==k2.
//   LUT interp error ~2e-2 in f-space attenuates by C6*M_INV*4 ~ 3.5e-5
//   into the output -> ~1e-6, 500x under the 1.33e-3 threshold.)
// ---------------------------------------------------------------------------
__launch_bounds__(256)
__global__ void rk4_rbf_kernel(const vfloat2* __restrict__ u2,
                               const vfloat4* __restrict__ states4,
                               const float*  __restrict__ centers,
                               const float*  __restrict__ log_sigmas,
                               const float*  __restrict__ wts,
                               const float*  __restrict__ bptr,
                               vfloat4* __restrict__ out4,
                               int n_pairs) {
    __shared__ float4 P[K_RBF];     // {A, B, E, w} per RBF
    __shared__ float  F[LUT_N];     // f(x_i), 1 KB

    if (threadIdx.x < K_RBF) {
        const float LOG2E = 1.4426950408889634f;
        int k = threadIdx.x;
        float s  = __expf(log_sigmas[k]);
        float s2 = s * s;
        float c  = centers[k];
        P[k] = make_float4(-s2 * LOG2E,                 // A
                           2.0f * s2 * c * LOG2E,       // B
                           -s2 * c * c * LOG2E,         // E
                           wts[k]);                     // w
    }
    __syncthreads();

    {   // one LUT point per thread (blockDim.x == LUT_N == 256)
        const float H = (LUT_HI - LUT_LO) / (float)LUT_N;
        float xg = LUT_LO + (float)threadIdx.x * H;
        float fv = bptr[0];
#pragma unroll
        for (int k = 0; k < K_RBF; ++k) {
            float4 p = P[k];
            float q = fmaf(fmaf(p.x, xg, p.y), xg, p.z);
            fv = fmaf(p.w, EXP2(q), fv);
        }
        F[threadIdx.x] = fv;
    }
    __syncthreads();

    const float FVC = F_V_F + F_C_F;
    const float C6  = DT_F / 6.0f;
    const float C1  = 0.015f * M_INV_F;   // M_INV*(4h+DT)
    const float C2  = C6 * 0.015f;        // C6*(4h+DT)

    int stride = gridDim.x * blockDim.x;
    for (int i = blockIdx.x * blockDim.x + threadIdx.x; i < n_pairs; i += stride) {
        vfloat4 s  = __builtin_nontemporal_load(&states4[i]);  // y0a,y1a,y0b,y1b
        vfloat2 uu = __builtin_nontemporal_load(&u2[i]);

        float x[2]  = { s.y, s.w };     // y1 (y0 is dead)
        float uv[2] = { uu.x, uu.y };
        float o[4];
#pragma unroll
        for (int e = 0; e < 2; ++e) {
            float t   = (x[e] - LUT_LO) * LUT_INVH;
            t = fminf(fmaxf(t, 0.0f), (float)(LUT_N - 2) + 0.999f);
            int   idx = (int)t;
            float fr  = t - (float)idx;
            float f0  = F[idx];
            float df  = F[idx + 1] - f0;
            float f   = fmaf(fr, df, f0);           // f(x) incl. b
            float fp  = df * LUT_INVH;              // f'(x)

            float k1 = (uv[e] - FVC * x[e] - (OFFST_F + f)) * M_INV_F;
            float g  = 6.0f - C1 * (FVC + fp);
            o[2 * e]     = fmaf(C2, k1, DT_F * x[e]);   // st0
            o[2 * e + 1] = C6 * k1 * g;                 // st1
        }

        vfloat4 ov = { o[0], o[1], o[2], o[3] };
        __builtin_nontemporal_store(ov, &out4[i]);
    }
}

extern "C" void kernel_launch(void* const* d_in, const int* in_sizes, int n_in,
                              void* d_out, int out_size, void* d_ws, size_t ws_size,
                              hipStream_t stream) {
    const float* u        = (const float*)d_in[0];   // (B,)
    const float* states   = (const float*)d_in[1];   // (B,2)
    const float* centers  = (const float*)d_in[2];   // (32,)
    const float* logsig   = (const float*)d_in[3];   // (32,)
    const float* w        = (const float*)d_in[4];   // (32,)
    const float* b        = (const float*)d_in[5];   // (1,)

    int B = in_sizes[0];
    int n_pairs = B / 2;                             // 2,097,152
    int block = 256;                                 // == LUT_N
    int grid  = 2048;                                // grid-stride: 4 pairs/thread
    rk4_rbf_kernel<<<grid, block, 0, stream>>>(
        (const vfloat2*)u, (const vfloat4*)states,
        centers, logsig, w, b, (vfloat4*)d_out, n_pairs);
}